// Round 4
// baseline (2670.668 us; speedup 1.0000x reference)
//
#include <hip/hip_runtime.h>
#include <cstdint>
#include <cstddef>

#define TOKENS 4096
#define E_ 512
#define T_ 2048
#define H_ 8
#define L_ 6
#define FF_ 2048
#define V_ 32000

typedef unsigned short u16;
typedef __attribute__((ext_vector_type(8))) short short8;
typedef __attribute__((ext_vector_type(4))) float f32x4;

__device__ __forceinline__ u16 f2b(float f) {
  union { float f; unsigned u; } x; x.f = f;
  unsigned r = x.u + 0x7fffu + ((x.u >> 16) & 1u);
  return (u16)(r >> 16);
}

// async 16B/lane global->LDS. lds ptr must be wave-uniform; HW scatters lane i to l + i*16.
__device__ __forceinline__ void gload_lds16(const void* g, void* l) {
  __builtin_amdgcn_global_load_lds((__attribute__((address_space(1))) void*)(uintptr_t)g,
                                   (__attribute__((address_space(3))) void*)l, 16, 0, 0);
}

// ---------------------------------------------------------------------------
// GEMM (128x128 tile): final vocab projection only (8000 blocks).
// 2-phase double-buffered pipeline.
// ---------------------------------------------------------------------------
template<int BF16OUT, int RESID, int RELU>
__global__ __launch_bounds__(256) void gemm_bt(
    const u16* __restrict__ A, const u16* __restrict__ BT,
    const float* __restrict__ bias, const float* __restrict__ resid,
    void* __restrict__ outp, int M, int N, int K, int ldc)
{
  __shared__ u16 a_sm[2][128 * 32];
  __shared__ u16 b_sm[2][128 * 32];
  const int tid  = threadIdx.x;
  const int wave = tid >> 6;
  const int lane = tid & 63;
  const int l16  = lane & 15;
  const int quad = lane >> 4;
  const int bm = blockIdx.y << 7;
  const int bn = blockIdx.x << 7;
  const int wr = (wave >> 1) << 6;
  const int wc = (wave & 1) << 6;

  const int srow = tid >> 2;          // 0..63
  const int soff = (tid & 3) << 3;    // element offset in 32-wide K slab
  const u16* ag0 = A  + (size_t)(bm + srow) * K + soff;
  const u16* ag1 = A  + (size_t)(bm + 64 + srow) * K + soff;
  const u16* bg0 = BT + (size_t)(bn + srow) * K + soff;
  const u16* bg1 = BT + (size_t)(bn + 64 + srow) * K + soff;

  auto stage = [&](int buf, int k0) {
    gload_lds16(ag0 + k0, a_sm[buf] + wave * 512);
    gload_lds16(ag1 + k0, a_sm[buf] + 2048 + wave * 512);
    gload_lds16(bg0 + k0, b_sm[buf] + wave * 512);
    gload_lds16(bg1 + k0, b_sm[buf] + 2048 + wave * 512);
  };

  f32x4 acc[4][4] = {};
  const int ksteps = K >> 5;
  stage(0, 0);
  int cur = 0;
  for (int t = 0; t < ksteps; ++t) {
    __syncthreads();
    if (t + 1 < ksteps) stage(cur ^ 1, (t + 1) << 5);
    short8 af[4], bf[4];
#pragma unroll
    for (int mt = 0; mt < 4; ++mt)
      af[mt] = *(const short8*)&a_sm[cur][(wr + mt * 16 + l16) * 32 + quad * 8];
#pragma unroll
    for (int nt = 0; nt < 4; ++nt)
      bf[nt] = *(const short8*)&b_sm[cur][(wc + nt * 16 + l16) * 32 + quad * 8];
#pragma unroll
    for (int mt = 0; mt < 4; ++mt)
#pragma unroll
      for (int nt = 0; nt < 4; ++nt)
        acc[mt][nt] = __builtin_amdgcn_mfma_f32_16x16x32_bf16(af[mt], bf[nt], acc[mt][nt], 0, 0, 0);
    cur ^= 1;
  }

#pragma unroll
  for (int mt = 0; mt < 4; ++mt) {
#pragma unroll
    for (int nt = 0; nt < 4; ++nt) {
      const int cg = bn + wc + nt * 16 + l16;
      const int rg = bm + wr + mt * 16 + quad * 4;
      const float bv = bias[cg];
#pragma unroll
      for (int i = 0; i < 4; ++i) {
        float v = acc[mt][nt][i] + bv;
        size_t idx = (size_t)(rg + i) * ldc + cg;
        if (RESID) v += resid[idx];
        if (RELU)  v = fmaxf(v, 0.f);
        if (BF16OUT) ((u16*)outp)[idx] = f2b(v);
        else         ((float*)outp)[idx] = v;
      }
    }
  }
}

// ---------------------------------------------------------------------------
// GEMM, 64x128 tile: per-layer QKV / FF1. 2-phase dbuf pipeline.
// ---------------------------------------------------------------------------
template<int BF16OUT, int RELU>
__global__ __launch_bounds__(256) void gemm_bt64(
    const u16* __restrict__ A, const u16* __restrict__ BT,
    const float* __restrict__ bias, void* __restrict__ outp,
    int M, int N, int K, int ldc)
{
  __shared__ u16 a_sm[2][64 * 32];
  __shared__ u16 b_sm[2][128 * 32];
  const int tid  = threadIdx.x;
  const int wave = tid >> 6;
  const int lane = tid & 63;
  const int l16  = lane & 15;
  const int quad = lane >> 4;
  const int bm = blockIdx.y << 6;
  const int bn = blockIdx.x << 7;
  const int wr = (wave >> 1) << 5;    // 0 or 32
  const int wc = (wave & 1) << 6;     // 0 or 64

  const int srow = tid >> 2;          // 0..63
  const int soff = (tid & 3) << 3;
  const u16* ag  = A  + (size_t)(bm + srow) * K + soff;
  const u16* bg0 = BT + (size_t)(bn + srow) * K + soff;
  const u16* bg1 = BT + (size_t)(bn + 64 + srow) * K + soff;

  auto stage = [&](int buf, int k0) {
    gload_lds16(ag  + k0, a_sm[buf] + wave * 512);
    gload_lds16(bg0 + k0, b_sm[buf] + wave * 512);
    gload_lds16(bg1 + k0, b_sm[buf] + 2048 + wave * 512);
  };

  f32x4 acc[2][4] = {};
  const int ksteps = K >> 5;
  stage(0, 0);
  int cur = 0;
  for (int t = 0; t < ksteps; ++t) {
    __syncthreads();
    if (t + 1 < ksteps) stage(cur ^ 1, (t + 1) << 5);
    short8 af[2], bf[4];
#pragma unroll
    for (int mt = 0; mt < 2; ++mt)
      af[mt] = *(const short8*)&a_sm[cur][(wr + mt * 16 + l16) * 32 + quad * 8];
#pragma unroll
    for (int nt = 0; nt < 4; ++nt)
      bf[nt] = *(const short8*)&b_sm[cur][(wc + nt * 16 + l16) * 32 + quad * 8];
#pragma unroll
    for (int mt = 0; mt < 2; ++mt)
#pragma unroll
      for (int nt = 0; nt < 4; ++nt)
        acc[mt][nt] = __builtin_amdgcn_mfma_f32_16x16x32_bf16(af[mt], bf[nt], acc[mt][nt], 0, 0, 0);
    cur ^= 1;
  }

#pragma unroll
  for (int mt = 0; mt < 2; ++mt) {
#pragma unroll
    for (int nt = 0; nt < 4; ++nt) {
      const int cg = bn + wc + nt * 16 + l16;
      const int rg = bm + wr + mt * 16 + quad * 4;
      const float bv = bias[cg];
#pragma unroll
      for (int i = 0; i < 4; ++i) {
        float v = acc[mt][nt][i] + bv;
        size_t idx = (size_t)(rg + i) * ldc + cg;
        if (RELU)  v = fmaxf(v, 0.f);
        if (BF16OUT) ((u16*)outp)[idx] = f2b(v);
        else         ((float*)outp)[idx] = v;
      }
    }
  }
}

// ---------------------------------------------------------------------------
// Split-K GEMM (64x128 tile, grid (4, 64, Z)) with FUSED reduce+resid+LN.
// Each block writes its fp32 partial to part[z], fences, bumps cnt[bm-stripe].
// The LAST of the 4*Z contributor blocks for a 64-row stripe re-reads the
// partials, adds h + bias, writes h, and emits LN (DOLN=1 -> y bf16) or a
// plain bf16 cast (DOLN=0). Device-scope fences per G12/G16; cnt self-cleans
// (reducer resets to 0) and is re-zeroed each call by the embed kernel
// (workspace is re-poisoned between bench iterations).
// ---------------------------------------------------------------------------
template<int DOLN, int Z>
__global__ __launch_bounds__(256) void gemm_skr64(
    const u16* __restrict__ A, const u16* __restrict__ BT,
    float* __restrict__ part, int* __restrict__ cnt,
    const float* __restrict__ bias, float* __restrict__ h,
    const float* __restrict__ sc, const float* __restrict__ bi,
    u16* __restrict__ yout, int lda, int kLen)
{
  __shared__ u16 a_sm[2][64 * 32];
  __shared__ u16 b_sm[2][128 * 32];
  const int tid  = threadIdx.x;
  const int wave = tid >> 6;
  const int lane = tid & 63;
  const int l16  = lane & 15;
  const int quad = lane >> 4;
  const int bm = blockIdx.y << 6;
  const int bn = blockIdx.x << 7;
  const int wr = (wave >> 1) << 5;
  const int wc = (wave & 1) << 6;

  const u16* Ab = A  + (size_t)blockIdx.z * kLen;
  const u16* Bb = BT + (size_t)blockIdx.z * kLen;

  const int srow = tid >> 2;
  const int soff = (tid & 3) << 3;
  const u16* ag  = Ab + (size_t)(bm + srow) * lda + soff;
  const u16* bg0 = Bb + (size_t)(bn + srow) * lda + soff;
  const u16* bg1 = Bb + (size_t)(bn + 64 + srow) * lda + soff;

  auto stage = [&](int buf, int k0) {
    gload_lds16(ag  + k0, a_sm[buf] + wave * 512);
    gload_lds16(bg0 + k0, b_sm[buf] + wave * 512);
    gload_lds16(bg1 + k0, b_sm[buf] + 2048 + wave * 512);
  };

  f32x4 acc[2][4] = {};
  const int ksteps = kLen >> 5;
  stage(0, 0);
  int cur = 0;
  for (int t = 0; t < ksteps; ++t) {
    __syncthreads();
    if (t + 1 < ksteps) stage(cur ^ 1, (t + 1) << 5);
    short8 af[2], bf[4];
#pragma unroll
    for (int mt = 0; mt < 2; ++mt)
      af[mt] = *(const short8*)&a_sm[cur][(wr + mt * 16 + l16) * 32 + quad * 8];
#pragma unroll
    for (int nt = 0; nt < 4; ++nt)
      bf[nt] = *(const short8*)&b_sm[cur][(wc + nt * 16 + l16) * 32 + quad * 8];
#pragma unroll
    for (int mt = 0; mt < 2; ++mt)
#pragma unroll
      for (int nt = 0; nt < 4; ++nt)
        acc[mt][nt] = __builtin_amdgcn_mfma_f32_16x16x32_bf16(af[mt], bf[nt], acc[mt][nt], 0, 0, 0);
    cur ^= 1;
  }

  // contributor: write fp32 partial
  float* out = part + (size_t)blockIdx.z * (TOKENS * 512);
#pragma unroll
  for (int mt = 0; mt < 2; ++mt) {
#pragma unroll
    for (int nt = 0; nt < 4; ++nt) {
      const int cg = bn + wc + nt * 16 + l16;
      const int rg = bm + wr + mt * 16 + quad * 4;
#pragma unroll
      for (int i = 0; i < 4; ++i)
        out[(size_t)(rg + i) * 512 + cg] = acc[mt][nt][i];
    }
  }
  __threadfence();  // release partials before signaling

  __shared__ int isLast;
  if (tid == 0) {
    const int old = atomicAdd(&cnt[blockIdx.y], 1);
    const int last = (old == (int)(gridDim.x * gridDim.z) - 1);
    if (last) atomicExch(&cnt[blockIdx.y], 0);  // self-clean for next use
    isLast = last;
  }
  __syncthreads();
  if (!isLast) return;
  __threadfence();  // acquire: invalidate stale cached partials

  // reducer: rows bm..bm+63, all 512 cols. 4 threads/row, interleaved float4s.
  const int r  = bm + (tid >> 2);
  const int c4 = (tid & 3) << 2;
  float4 v[32];
#pragma unroll
  for (int i = 0; i < 32; ++i) {
    const int col = i * 16 + c4;
    float4 a = *(const float4*)&h[(size_t)r * 512 + col];
    const float4 b = *(const float4*)&bias[col];
    a.x += b.x; a.y += b.y; a.z += b.z; a.w += b.w;
#pragma unroll
    for (int z = 0; z < Z; ++z) {
      const float4 p = *(const float4*)&part[((size_t)z * TOKENS + r) * 512 + col];
      a.x += p.x; a.y += p.y; a.z += p.z; a.w += p.w;
    }
    *(float4*)&h[(size_t)r * 512 + col] = a;
    v[i] = a;
  }
  float s = 0.f, q = 0.f;
#pragma unroll
  for (int i = 0; i < 32; ++i) {
    s += (v[i].x + v[i].y) + (v[i].z + v[i].w);
    q += (v[i].x * v[i].x + v[i].y * v[i].y) + (v[i].z * v[i].z + v[i].w * v[i].w);
  }
  s += __shfl_xor(s, 1); s += __shfl_xor(s, 2);   // quad reduce (4 threads/row)
  q += __shfl_xor(q, 1); q += __shfl_xor(q, 2);
  const float mu = s * (1.f / 512.f);
  const float var = q * (1.f / 512.f) - mu * mu;
  const float rstd = rsqrtf(var + 1e-5f);
#pragma unroll
  for (int i = 0; i < 32; ++i) {
    const int col = i * 16 + c4;
    float y0, y1, y2, y3;
    if (DOLN) {
      const float4 s4 = *(const float4*)&sc[col];
      const float4 b4 = *(const float4*)&bi[col];
      y0 = (v[i].x - mu) * rstd * s4.x + b4.x;
      y1 = (v[i].y - mu) * rstd * s4.y + b4.y;
      y2 = (v[i].z - mu) * rstd * s4.z + b4.z;
      y3 = (v[i].w - mu) * rstd * s4.w + b4.w;
    } else {
      y0 = v[i].x; y1 = v[i].y; y2 = v[i].z; y3 = v[i].w;
    }
    uint2 pk;
    pk.x = ((unsigned)f2b(y1) << 16) | (unsigned)f2b(y0);
    pk.y = ((unsigned)f2b(y3) << 16) | (unsigned)f2b(y2);
    *(uint2*)(yout + (size_t)r * 512 + col) = pk;
  }
}

// ---------------------------------------------------------------------------
// Flash-style causal attention, KVBLK=64, T2 XOR-swizzled LDS, 2-phase
// double-buffered K/V pipeline. LOAD-BALANCED j remap: block pairs
// (bx,by)/(bx,by+8) co-reside under round-robin dispatch; giving them j and
// 31-j makes per-CU work constant (33 tile-units vs worst-case 64).
// ---------------------------------------------------------------------------
__global__ __launch_bounds__(256) void attn_kernel(const u16* __restrict__ qkv,
                                                   u16* __restrict__ o)
{
  __shared__ u16 k_sm[2][64 * 64];    // [key][d], swizzled
  __shared__ u16 vT_sm[2][64 * 64];   // [d][key], swizzled
  __shared__ u16 p_sm[4 * 16 * 64];   // per-wave P [qrow][key], swizzled
  const int tid  = threadIdx.x;
  const int wave = tid >> 6;
  const int lane = tid & 63;
  const int l16  = lane & 15;
  const int quad = lane >> 4;
  const int bh = blockIdx.y;
  const int j  = (bh < 8) ? blockIdx.x : 31 - blockIdx.x;  // balanced q-tile id
  const int b  = bh >> 3, h = bh & 7;
  const size_t base = (size_t)b * T_ * 1536;

  const int qrow = j * 64 + wave * 16 + l16;
  short8 aq[2];
#pragma unroll
  for (int half = 0; half < 2; ++half)
    aq[half] = *(const short8*)&qkv[base + (size_t)qrow * 1536 + h * 64 + half * 32 + quad * 8];

  f32x4 oacc[4] = {};
  float m_i[4] = {-INFINITY, -INFINITY, -INFINITY, -INFINITY};
  float l_i[4] = {0.f, 0.f, 0.f, 0.f};

  const int ksrc = ((tid & 7) ^ ((tid >> 3) & 7)) * 8;
  auto stageK = [&](int kt, int buf) {
    gload_lds16(qkv + base + (size_t)(kt * 64 + (tid >> 3)) * 1536 + 512 + h * 64 + ksrc,
                k_sm[buf] + wave * 512);
    gload_lds16(qkv + base + (size_t)(kt * 64 + 32 + (tid >> 3)) * 1536 + 512 + h * 64 + ksrc,
                k_sm[buf] + 2048 + wave * 512);
  };
  const int vt = tid >> 2, vd0 = (tid & 3) * 16;
  auto loadV = [&](int kt, short8* vr) {
    const u16* vp = &qkv[base + (size_t)(kt * 64 + vt) * 1536 + 1024 + h * 64 + vd0];
    vr[0] = *(const short8*)vp;
    vr[1] = *(const short8*)(vp + 8);
  };
  auto writeV = [&](int buf, const short8* vr) {
#pragma unroll
    for (int i = 0; i < 8; ++i) vT_sm[buf][(vd0 + i) * 64 + (vt ^ (i << 3))] = (u16)vr[0][i];
#pragma unroll
    for (int i = 0; i < 8; ++i) vT_sm[buf][(vd0 + 8 + i) * 64 + (vt ^ (i << 3))] = (u16)vr[1][i];
  };

  const int nkt = j + 1;
  short8 vr[2], vrn[2];
  stageK(0, 0);
  loadV(0, vr);
  writeV(0, vr);
  int cur = 0;
  for (int kt = 0; kt < nkt; ++kt) {
    __syncthreads();
    if (kt + 1 < nkt) { stageK(kt + 1, cur ^ 1); loadV(kt + 1, vrn); }

    f32x4 s[4] = {};
#pragma unroll
    for (int nt = 0; nt < 4; ++nt)
#pragma unroll
      for (int half = 0; half < 2; ++half) {
        short8 bk = *(const short8*)&k_sm[cur][(nt * 16 + l16) * 64 +
                                              (((half * 4 + quad) ^ (l16 & 7)) << 3)];
        s[nt] = __builtin_amdgcn_mfma_f32_16x16x32_bf16(aq[half], bk, s[nt], 0, 0, 0);
      }
#pragma unroll
    for (int nt = 0; nt < 4; ++nt)
#pragma unroll
      for (int i = 0; i < 4; ++i) {
        const int col = kt * 64 + nt * 16 + l16;
        const int row = j * 64 + wave * 16 + quad * 4 + i;
        float sv = s[nt][i] * 0.125f;
        s[nt][i] = (col <= row) ? sv : -INFINITY;
      }
    float rm[4], mn[4], alpha[4], rs[4], p[4][4];
#pragma unroll
    for (int i = 0; i < 4; ++i)
      rm[i] = fmaxf(fmaxf(s[0][i], s[1][i]), fmaxf(s[2][i], s[3][i]));
#pragma unroll
    for (int off = 1; off < 16; off <<= 1)
#pragma unroll
      for (int i = 0; i < 4; ++i) rm[i] = fmaxf(rm[i], __shfl_xor(rm[i], off));
#pragma unroll
    for (int i = 0; i < 4; ++i) {
      mn[i] = fmaxf(m_i[i], rm[i]);
      alpha[i] = __expf(m_i[i] - mn[i]);
      m_i[i] = mn[i];
#pragma unroll
      for (int nt = 0; nt < 4; ++nt) p[nt][i] = __expf(s[nt][i] - mn[i]);
      rs[i] = (p[0][i] + p[1][i]) + (p[2][i] + p[3][i]);
    }
#pragma unroll
    for (int off = 1; off < 16; off <<= 1)
#pragma unroll
      for (int i = 0; i < 4; ++i) rs[i] += __shfl_xor(rs[i], off);
#pragma unroll
    for (int i = 0; i < 4; ++i) l_i[i] = l_i[i] * alpha[i] + rs[i];
#pragma unroll
    for (int nt = 0; nt < 4; ++nt)
#pragma unroll
      for (int i = 0; i < 4; ++i) oacc[nt][i] *= alpha[i];
    u16* pw = p_sm + wave * 1024;
#pragma unroll
    for (int i = 0; i < 4; ++i) {
      const int pr = quad * 4 + i;
#pragma unroll
      for (int nt = 0; nt < 4; ++nt)
        pw[pr * 64 + ((nt * 16 + l16) ^ ((pr & 7) << 3))] = f2b(p[nt][i]);
    }
    asm volatile("s_waitcnt lgkmcnt(0)" ::: "memory");
    short8 pf[2];
#pragma unroll
    for (int kh = 0; kh < 2; ++kh)
      pf[kh] = *(const short8*)&pw[l16 * 64 + (((kh * 4 + quad) ^ (l16 & 7)) << 3)];
#pragma unroll
    for (int nt = 0; nt < 4; ++nt)
#pragma unroll
      for (int kh = 0; kh < 2; ++kh) {
        short8 bv = *(const short8*)&vT_sm[cur][(nt * 16 + l16) * 64 +
                                               (((kh * 4 + quad) ^ (l16 & 7)) << 3)];
        oacc[nt] = __builtin_amdgcn_mfma_f32_16x16x32_bf16(pf[kh], bv, oacc[nt], 0, 0, 0);
      }

    if (kt + 1 < nkt) writeV(cur ^ 1, vrn);
    cur ^= 1;
  }
#pragma unroll
  for (int nt = 0; nt < 4; ++nt)
#pragma unroll
    for (int i = 0; i < 4; ++i) {
      const int row = j * 64 + wave * 16 + quad * 4 + i;
      const float ov = oacc[nt][i] / l_i[i];
      o[(size_t)(b * T_ + row) * 512 + h * 64 + nt * 16 + l16] = f2b(ov);
    }
}

// ---------------------------------------------------------------------------
// Row LN helper (embed kernel only).
// ---------------------------------------------------------------------------
__device__ __forceinline__ void ln_emit(float2 hv, const float* __restrict__ sc,
                                        const float* __restrict__ bi, int tid,
                                        unsigned* __restrict__ yrow)
{
  float s = hv.x + hv.y;
  float q = hv.x * hv.x + hv.y * hv.y;
  for (int off = 32; off; off >>= 1) { s += __shfl_down(s, off); q += __shfl_down(q, off); }
  __shared__ float red[8];
  const int wave = tid >> 6, lane = tid & 63;
  if (!lane) { red[wave] = s; red[4 + wave] = q; }
  __syncthreads();
  if (tid == 0) {
    float ts = 0, tq = 0;
    for (int w = 0; w < 4; ++w) { ts += red[w]; tq += red[4 + w]; }
    red[0] = ts; red[4] = tq;
  }
  __syncthreads();
  const float mu = red[0] * (1.f / 512.f);
  const float var = red[4] * (1.f / 512.f) - mu * mu;
  const float rstd = rsqrtf(var + 1e-5f);
  const float y0 = (hv.x - mu) * rstd * sc[tid * 2]     + bi[tid * 2];
  const float y1 = (hv.y - mu) * rstd * sc[tid * 2 + 1] + bi[tid * 2 + 1];
  yrow[tid] = ((unsigned)f2b(y1) << 16) | (unsigned)f2b(y0);
}

// ---------------------------------------------------------------------------
// Embedding + ln1(layer 0), PLUS housekeeping folded in: bias_cat for the
// QKV bias (blocks 0..35) and split-K counter zeroing (block 0; workspace is
// poisoned between bench iterations so this must run every call).
// ---------------------------------------------------------------------------
__global__ __launch_bounds__(256) void embed_ln_kernel(const int* __restrict__ x,
                                                       const float* __restrict__ tok,
                                                       const float* __restrict__ pos,
                                                       const float* __restrict__ sc,
                                                       const float* __restrict__ bi,
                                                       const float* __restrict__ bq,
                                                       const float* __restrict__ bk,
                                                       const float* __restrict__ bv,
                                                       float* __restrict__ bqkv,
                                                       int* __restrict__ cnt,
                                                       float* __restrict__ h,
                                                       u16* __restrict__ y)
{
  const int row = blockIdx.x, tid = threadIdx.x;
  if (row == 0 && tid < 64) cnt[tid] = 0;
  if (row < 36) {
    const int i = row * 256 + tid;
    if (i < L_ * 1536) {
      const int l = i / 1536, c = i % 1536;
      bqkv[i] = (c < 512) ? bq[l * 512 + c]
              : (c < 1024) ? bk[l * 512 + c - 512] : bv[l * 512 + c - 1024];
    }
  }
  const int t = row & (T_ - 1);
  const int tk = x[row];
  const float2 a = ((const float2*)tok)[(size_t)tk * 256 + tid];
  const float2 p = ((const float2*)pos)[(size_t)t * 256 + tid];
  float2 hv = make_float2(a.x + p.x, a.y + p.y);
  ((float2*)(h + (size_t)row * 512))[tid] = hv;
  ln_emit(hv, sc, bi, tid, (unsigned*)(y + (size_t)row * 512));
}

// ---------------------------------------------------------------------------
// ALL weight transposes (fp32 -> bf16, [K][N] -> [N][K]) in ONE launch.
// Flat block id decodes which weight/tile. 34432 blocks of (32,8).
// ---------------------------------------------------------------------------
__global__ void transW_all(const float* __restrict__ Wq, const float* __restrict__ Wk,
                           const float* __restrict__ Wv, const float* __restrict__ Wo,
                           const float* __restrict__ W1, const float* __restrict__ W2,
                           const float* __restrict__ Wout,
                           u16* __restrict__ qkvT, u16* __restrict__ WoT,
                           u16* __restrict__ W1T, u16* __restrict__ W2T,
                           u16* __restrict__ WoutT)
{
  __shared__ float tile[32][33];
  int f = blockIdx.x;
  const float* S; u16* D; int N, Kd, n0, k0;
  if (f < 16000) {                       // Wout [512][32000] -> WoutT [32000][512]
    S = Wout; D = WoutT; N = 32000; Kd = 512;
    n0 = (f % 1000) * 32; k0 = (f / 1000) * 32;
  } else {
    f -= 16000;
    const int l = f / 3072, r = f % 3072;
    if (r < 1024) {                      // Wq/Wk/Wv/Wo [512][512]
      const int w = r >> 8, rr = r & 255;
      S = (w == 0 ? Wq : w == 1 ? Wk : w == 2 ? Wv : Wo) + (size_t)l * 512 * 512;
      D = (w < 3) ? qkvT + (size_t)l * 1536 * 512 + (size_t)w * 512 * 512
                  : WoT + (size_t)l * 512 * 512;
      N = 512; Kd = 512;
      n0 = (rr & 15) * 32; k0 = (rr >> 4) * 32;
    } else if (r < 2048) {               // W1 [512][2048] -> W1T [2048][512]
      const int rr = r - 1024;
      S = W1 + (size_t)l * 512 * 2048; D = W1T + (size_t)l * 2048 * 512;
      N = 2048; Kd = 512;
      n0 = (rr & 63) * 32; k0 = (rr >> 6) * 32;
    } else {                             // W2 [2048][512] -> W2T [512][2048]
      const int rr = r - 2048;
      S = W2 + (size_t)l * 2048 * 512; D = W2T + (size_t)l * 512 * 2048;
      N = 512; Kd = 2048;
      n0 = (rr & 15) * 32; k0 = (rr >> 4) * 32;
    }
  }
  const int tx = threadIdx.x, ty = threadIdx.y;
#pragma unroll
  for (int i = 0; i < 4; ++i)
    tile[ty + 8 * i][tx] = S[(size_t)(k0 + ty + 8 * i) * N + n0 + tx];
  __syncthreads();
#pragma unroll
  for (int i = 0; i < 4; ++i)
    D[(size_t)(n0 + ty + 8 * i) * Kd + k0 + tx] = f2b(tile[tx][ty + 8 * i]);
}

// ---------------------------------------------------------------------------
extern "C" void kernel_launch(void* const* d_in, const int* in_sizes, int n_in,
                              void* d_out, int out_size, void* d_ws, size_t ws_size,
                              hipStream_t stream) {
  const int*   x     = (const int*)d_in[0];
  const float* tok   = (const float*)d_in[1];
  const float* pos   = (const float*)d_in[2];
  const float* Wq    = (const float*)d_in[3];
  const float* bq    = (const float*)d_in[4];
  const float* Wk    = (const float*)d_in[5];
  const float* bk    = (const float*)d_in[6];
  const float* Wv    = (const float*)d_in[7];
  const float* bv    = (const float*)d_in[8];
  const float* Wo    = (const float*)d_in[9];
  const float* bo    = (const float*)d_in[10];
  const float* ln1s  = (const float*)d_in[11];
  const float* ln1b  = (const float*)d_in[12];
  const float* ln2s  = (const float*)d_in[13];
  const float* ln2b  = (const float*)d_in[14];
  const float* W1    = (const float*)d_in[15];
  const float* b1    = (const float*)d_in[16];
  const float* W2    = (const float*)d_in[17];
  const float* b2    = (const float*)d_in[18];
  const float* Wout  = (const float*)d_in[19];
  const float* bout  = (const float*)d_in[20];

  char* ws = (char*)d_ws;
  size_t off = 0;
  auto alloc = [&](size_t bytes) { char* p = ws + off; off += (bytes + 255) & ~(size_t)255; return p; };
  u16*   qkvT  = (u16*)alloc((size_t)L_ * 1536 * 512 * 2);
  u16*   WoT   = (u16*)alloc((size_t)L_ * 512 * 512 * 2);
  u16*   W1T   = (u16*)alloc((size_t)L_ * 2048 * 512 * 2);
  u16*   W2T   = (u16*)alloc((size_t)L_ * 512 * 2048 * 2);
  u16*   WoutT = (u16*)alloc((size_t)V_ * 512 * 2);
  float* bqkv  = (float*)alloc((size_t)L_ * 1536 * 4);
  float* h     = (float*)alloc((size_t)TOKENS * 512 * 4);
  u16*   y     = (u16*)alloc((size_t)TOKENS * 512 * 2);
  u16*   qkv   = (u16*)alloc((size_t)TOKENS * 1536 * 2);
  u16*   obuf  = (u16*)alloc((size_t)TOKENS * 512 * 2);
  u16*   ff    = (u16*)alloc((size_t)TOKENS * 2048 * 2);
  u16*   hb    = (u16*)alloc((size_t)TOKENS * 512 * 2);
  float* part  = (float*)alloc((size_t)4 * TOKENS * 512 * 4);  // split-K partials
  int*   cnt   = (int*)alloc(64 * sizeof(int));                // stripe counters
  (void)ws_size; (void)in_sizes; (void)n_in; (void)out_size;

  // ALL weight prep in one launch (was 7)
  transW_all<<<34432, dim3(32, 8), 0, stream>>>(Wq, Wk, Wv, Wo, W1, W2, Wout,
                                                qkvT, WoT, W1T, W2T, WoutT);

  // embed + ln1(layer 0) + bias_cat + counter zeroing
  embed_ln_kernel<<<TOKENS, 256, 0, stream>>>(x, tok, pos, ln1s, ln1b,
                                              bq, bk, bv, bqkv, cnt, h, y);

  for (int l = 0; l < L_; ++l) {
    // QKV: 768 blocks (3/CU)
    gemm_bt64<1, 0><<<dim3(12, 64), 256, 0, stream>>>(
        y, qkvT + (size_t)l * 1536 * 512, bqkv + l * 1536, qkv, TOKENS, 1536, 512, 1536);
    attn_kernel<<<dim3(32, 16), 256, 0, stream>>>(qkv, obuf);
    // Wo projection: split-K=2 + FUSED reduce+resid+ln2 -> y
    gemm_skr64<1, 2><<<dim3(4, 64, 2), 256, 0, stream>>>(
        obuf, WoT + (size_t)l * 512 * 512, part, cnt, bo + l * 512, h,
        ln2s + l * 512, ln2b + l * 512, y, 512, 256);
    // FF1: 1024 blocks (4/CU)
    gemm_bt64<1, 1><<<dim3(16, 64), 256, 0, stream>>>(
        y, W1T + (size_t)l * 2048 * 512, b1 + l * 2048, ff, TOKENS, 2048, 512, 2048);
    // FF2: split-K=2 + FUSED reduce+resid+{ln1(l+1) | bf16 cast}
    if (l < L_ - 1)
      gemm_skr64<1, 2><<<dim3(4, 64, 2), 256, 0, stream>>>(
          ff, W2T + (size_t)l * 512 * 2048, part, cnt, b2 + l * 512, h,
          ln1s + (l + 1) * 512, ln1b + (l + 1) * 512, y, 2048, 1024);
    else
      gemm_skr64<0, 2><<<dim3(4, 64, 2), 256, 0, stream>>>(
          ff, W2T + (size_t)l * 512 * 2048, part, cnt, b2 + l * 512, h,
          nullptr, nullptr, hb, 2048, 1024);
  }

  gemm_bt<0, 0, 0><<<dim3(250, 32), 256, 0, stream>>>(
      hb, WoutT, bout, nullptr, (float*)d_out, TOKENS, V_, 512, V_);
}

// Round 5
// 1730.136 us; speedup vs baseline: 1.5436x; 1.5436x over previous
//
#include <hip/hip_runtime.h>
#include <cstdint>
#include <cstddef>

#define TOKENS 4096
#define E_ 512
#define T_ 2048
#define H_ 8
#define L_ 6
#define FF_ 2048
#define V_ 32000

typedef unsigned short u16;
typedef __attribute__((ext_vector_type(8))) short short8;
typedef __attribute__((ext_vector_type(4))) float f32x4;

__device__ __forceinline__ u16 f2b(float f) {
  union { float f; unsigned u; } x; x.f = f;
  unsigned r = x.u + 0x7fffu + ((x.u >> 16) & 1u);
  return (u16)(r >> 16);
}

// async 16B/lane global->LDS. lds ptr must be wave-uniform; HW scatters lane i to l + i*16.
__device__ __forceinline__ void gload_lds16(const void* g, void* l) {
  __builtin_amdgcn_global_load_lds((__attribute__((address_space(1))) void*)(uintptr_t)g,
                                   (__attribute__((address_space(3))) void*)l, 16, 0, 0);
}

// ---------------------------------------------------------------------------
// GEMM (128x128 tile): final vocab projection only (8000 blocks).
// 2-phase dbuf pipeline + bijective XCD swizzle (nwg%8==0) + non-temporal
// fp32 stores (524MB logits are never re-read; keep WoutT in cache).
// ---------------------------------------------------------------------------
template<int BF16OUT, int RELU>
__global__ __launch_bounds__(256) void gemm_bt(
    const u16* __restrict__ A, const u16* __restrict__ BT,
    const float* __restrict__ bias, void* __restrict__ outp,
    int M, int N, int K, int ldc)
{
  __shared__ u16 a_sm[2][128 * 32];
  __shared__ u16 b_sm[2][128 * 32];
  const int tid  = threadIdx.x;
  const int wave = tid >> 6;
  const int lane = tid & 63;
  const int l16  = lane & 15;
  const int quad = lane >> 4;
  // XCD-aware bijective swizzle: consecutive work ids land on one XCD's L2.
  int id = blockIdx.y * gridDim.x + blockIdx.x;
  const int cpx = (gridDim.x * gridDim.y) >> 3;
  id = (id & 7) * cpx + (id >> 3);
  const int bm = (id / gridDim.x) << 7;
  const int bn = (id % gridDim.x) << 7;
  const int wr = (wave >> 1) << 6;
  const int wc = (wave & 1) << 6;

  const int srow = tid >> 2;          // 0..63
  const int soff = (tid & 3) << 3;    // element offset in 32-wide K slab
  const u16* ag0 = A  + (size_t)(bm + srow) * K + soff;
  const u16* ag1 = A  + (size_t)(bm + 64 + srow) * K + soff;
  const u16* bg0 = BT + (size_t)(bn + srow) * K + soff;
  const u16* bg1 = BT + (size_t)(bn + 64 + srow) * K + soff;

  auto stage = [&](int buf, int k0) {
    gload_lds16(ag0 + k0, a_sm[buf] + wave * 512);
    gload_lds16(ag1 + k0, a_sm[buf] + 2048 + wave * 512);
    gload_lds16(bg0 + k0, b_sm[buf] + wave * 512);
    gload_lds16(bg1 + k0, b_sm[buf] + 2048 + wave * 512);
  };

  f32x4 acc[4][4] = {};
  const int ksteps = K >> 5;
  stage(0, 0);
  int cur = 0;
  for (int t = 0; t < ksteps; ++t) {
    __syncthreads();
    if (t + 1 < ksteps) stage(cur ^ 1, (t + 1) << 5);
    short8 af[4], bf[4];
#pragma unroll
    for (int mt = 0; mt < 4; ++mt)
      af[mt] = *(const short8*)&a_sm[cur][(wr + mt * 16 + l16) * 32 + quad * 8];
#pragma unroll
    for (int nt = 0; nt < 4; ++nt)
      bf[nt] = *(const short8*)&b_sm[cur][(wc + nt * 16 + l16) * 32 + quad * 8];
#pragma unroll
    for (int mt = 0; mt < 4; ++mt)
#pragma unroll
      for (int nt = 0; nt < 4; ++nt)
        acc[mt][nt] = __builtin_amdgcn_mfma_f32_16x16x32_bf16(af[mt], bf[nt], acc[mt][nt], 0, 0, 0);
    cur ^= 1;
  }

#pragma unroll
  for (int mt = 0; mt < 4; ++mt) {
#pragma unroll
    for (int nt = 0; nt < 4; ++nt) {
      const int cg = bn + wc + nt * 16 + l16;
      const int rg = bm + wr + mt * 16 + quad * 4;
      const float bv = bias[cg];
#pragma unroll
      for (int i = 0; i < 4; ++i) {
        float v = acc[mt][nt][i] + bv;
        size_t idx = (size_t)(rg + i) * ldc + cg;
        if (RELU)  v = fmaxf(v, 0.f);
        if (BF16OUT) ((u16*)outp)[idx] = f2b(v);
        else         __builtin_nontemporal_store(v, (float*)outp + idx);
      }
    }
  }
}

// ---------------------------------------------------------------------------
// GEMM, 64x128 tile: per-layer QKV / FF1. 2-phase dbuf pipeline.
// ---------------------------------------------------------------------------
template<int BF16OUT, int RELU>
__global__ __launch_bounds__(256) void gemm_bt64(
    const u16* __restrict__ A, const u16* __restrict__ BT,
    const float* __restrict__ bias, void* __restrict__ outp,
    int M, int N, int K, int ldc)
{
  __shared__ u16 a_sm[2][64 * 32];
  __shared__ u16 b_sm[2][128 * 32];
  const int tid  = threadIdx.x;
  const int wave = tid >> 6;
  const int lane = tid & 63;
  const int l16  = lane & 15;
  const int quad = lane >> 4;
  const int bm = blockIdx.y << 6;
  const int bn = blockIdx.x << 7;
  const int wr = (wave >> 1) << 5;    // 0 or 32
  const int wc = (wave & 1) << 6;     // 0 or 64

  const int srow = tid >> 2;          // 0..63
  const int soff = (tid & 3) << 3;
  const u16* ag  = A  + (size_t)(bm + srow) * K + soff;
  const u16* bg0 = BT + (size_t)(bn + srow) * K + soff;
  const u16* bg1 = BT + (size_t)(bn + 64 + srow) * K + soff;

  auto stage = [&](int buf, int k0) {
    gload_lds16(ag  + k0, a_sm[buf] + wave * 512);
    gload_lds16(bg0 + k0, b_sm[buf] + wave * 512);
    gload_lds16(bg1 + k0, b_sm[buf] + 2048 + wave * 512);
  };

  f32x4 acc[2][4] = {};
  const int ksteps = K >> 5;
  stage(0, 0);
  int cur = 0;
  for (int t = 0; t < ksteps; ++t) {
    __syncthreads();
    if (t + 1 < ksteps) stage(cur ^ 1, (t + 1) << 5);
    short8 af[2], bf[4];
#pragma unroll
    for (int mt = 0; mt < 2; ++mt)
      af[mt] = *(const short8*)&a_sm[cur][(wr + mt * 16 + l16) * 32 + quad * 8];
#pragma unroll
    for (int nt = 0; nt < 4; ++nt)
      bf[nt] = *(const short8*)&b_sm[cur][(wc + nt * 16 + l16) * 32 + quad * 8];
#pragma unroll
    for (int mt = 0; mt < 2; ++mt)
#pragma unroll
      for (int nt = 0; nt < 4; ++nt)
        acc[mt][nt] = __builtin_amdgcn_mfma_f32_16x16x32_bf16(af[mt], bf[nt], acc[mt][nt], 0, 0, 0);
    cur ^= 1;
  }

#pragma unroll
  for (int mt = 0; mt < 2; ++mt) {
#pragma unroll
    for (int nt = 0; nt < 4; ++nt) {
      const int cg = bn + wc + nt * 16 + l16;
      const int rg = bm + wr + mt * 16 + quad * 4;
      const float bv = bias[cg];
#pragma unroll
      for (int i = 0; i < 4; ++i) {
        float v = acc[mt][nt][i] + bv;
        size_t idx = (size_t)(rg + i) * ldc + cg;
        if (RELU)  v = fmaxf(v, 0.f);
        if (BF16OUT) ((u16*)outp)[idx] = f2b(v);
        else         ((float*)outp)[idx] = v;
      }
    }
  }
}

// ---------------------------------------------------------------------------
// Split-K GEMM partial, 64x128 tile (NO device-scope fences — the kernel
// boundary orders partials; round-3's fused atomic reduce cost one L2
// write-back per contributor block and regressed 800us).
// ---------------------------------------------------------------------------
__global__ __launch_bounds__(256) void gemm_sk64(
    const u16* __restrict__ A, const u16* __restrict__ BT,
    float* __restrict__ part, int M, int N, int lda, int kLen)
{
  __shared__ u16 a_sm[2][64 * 32];
  __shared__ u16 b_sm[2][128 * 32];
  const int tid  = threadIdx.x;
  const int wave = tid >> 6;
  const int lane = tid & 63;
  const int l16  = lane & 15;
  const int quad = lane >> 4;
  const int bm = blockIdx.y << 6;
  const int bn = blockIdx.x << 7;
  const int wr = (wave >> 1) << 5;
  const int wc = (wave & 1) << 6;

  const u16* Ab = A  + (size_t)blockIdx.z * kLen;
  const u16* Bb = BT + (size_t)blockIdx.z * kLen;

  const int srow = tid >> 2;
  const int soff = (tid & 3) << 3;
  const u16* ag  = Ab + (size_t)(bm + srow) * lda + soff;
  const u16* bg0 = Bb + (size_t)(bn + srow) * lda + soff;
  const u16* bg1 = Bb + (size_t)(bn + 64 + srow) * lda + soff;

  auto stage = [&](int buf, int k0) {
    gload_lds16(ag  + k0, a_sm[buf] + wave * 512);
    gload_lds16(bg0 + k0, b_sm[buf] + wave * 512);
    gload_lds16(bg1 + k0, b_sm[buf] + 2048 + wave * 512);
  };

  f32x4 acc[2][4] = {};
  const int ksteps = kLen >> 5;
  stage(0, 0);
  int cur = 0;
  for (int t = 0; t < ksteps; ++t) {
    __syncthreads();
    if (t + 1 < ksteps) stage(cur ^ 1, (t + 1) << 5);
    short8 af[2], bf[4];
#pragma unroll
    for (int mt = 0; mt < 2; ++mt)
      af[mt] = *(const short8*)&a_sm[cur][(wr + mt * 16 + l16) * 32 + quad * 8];
#pragma unroll
    for (int nt = 0; nt < 4; ++nt)
      bf[nt] = *(const short8*)&b_sm[cur][(wc + nt * 16 + l16) * 32 + quad * 8];
#pragma unroll
    for (int mt = 0; mt < 2; ++mt)
#pragma unroll
      for (int nt = 0; nt < 4; ++nt)
        acc[mt][nt] = __builtin_amdgcn_mfma_f32_16x16x32_bf16(af[mt], bf[nt], acc[mt][nt], 0, 0, 0);
    cur ^= 1;
  }

  float* out = part + (size_t)blockIdx.z * M * N;
#pragma unroll
  for (int mt = 0; mt < 2; ++mt) {
#pragma unroll
    for (int nt = 0; nt < 4; ++nt) {
      const int cg = bn + wc + nt * 16 + l16;
      const int rg = bm + wr + mt * 16 + quad * 4;
#pragma unroll
      for (int i = 0; i < 4; ++i)
        out[(size_t)(rg + i) * N + cg] = acc[mt][nt][i];
    }
  }
}

// ---------------------------------------------------------------------------
// Flash-style causal attention, KVBLK=64, T2 XOR-swizzled LDS, 2-phase
// double-buffered K/V pipeline. LOAD-BALANCED j remap: block pairs
// (bx,by)/(bx,by+8) co-reside under round-robin dispatch; giving them j and
// 31-j makes per-CU work constant (33 tile-units vs worst-case 64).
// ---------------------------------------------------------------------------
__global__ __launch_bounds__(256) void attn_kernel(const u16* __restrict__ qkv,
                                                   u16* __restrict__ o)
{
  __shared__ u16 k_sm[2][64 * 64];    // [key][d], swizzled
  __shared__ u16 vT_sm[2][64 * 64];   // [d][key], swizzled
  __shared__ u16 p_sm[4 * 16 * 64];   // per-wave P [qrow][key], swizzled
  const int tid  = threadIdx.x;
  const int wave = tid >> 6;
  const int lane = tid & 63;
  const int l16  = lane & 15;
  const int quad = lane >> 4;
  const int bh = blockIdx.y;
  const int j  = (bh < 8) ? blockIdx.x : 31 - blockIdx.x;  // balanced q-tile id
  const int b  = bh >> 3, h = bh & 7;
  const size_t base = (size_t)b * T_ * 1536;

  const int qrow = j * 64 + wave * 16 + l16;
  short8 aq[2];
#pragma unroll
  for (int half = 0; half < 2; ++half)
    aq[half] = *(const short8*)&qkv[base + (size_t)qrow * 1536 + h * 64 + half * 32 + quad * 8];

  f32x4 oacc[4] = {};
  float m_i[4] = {-INFINITY, -INFINITY, -INFINITY, -INFINITY};
  float l_i[4] = {0.f, 0.f, 0.f, 0.f};

  const int ksrc = ((tid & 7) ^ ((tid >> 3) & 7)) * 8;
  auto stageK = [&](int kt, int buf) {
    gload_lds16(qkv + base + (size_t)(kt * 64 + (tid >> 3)) * 1536 + 512 + h * 64 + ksrc,
                k_sm[buf] + wave * 512);
    gload_lds16(qkv + base + (size_t)(kt * 64 + 32 + (tid >> 3)) * 1536 + 512 + h * 64 + ksrc,
                k_sm[buf] + 2048 + wave * 512);
  };
  const int vt = tid >> 2, vd0 = (tid & 3) * 16;
  auto loadV = [&](int kt, short8* vr) {
    const u16* vp = &qkv[base + (size_t)(kt * 64 + vt) * 1536 + 1024 + h * 64 + vd0];
    vr[0] = *(const short8*)vp;
    vr[1] = *(const short8*)(vp + 8);
  };
  auto writeV = [&](int buf, const short8* vr) {
#pragma unroll
    for (int i = 0; i < 8; ++i) vT_sm[buf][(vd0 + i) * 64 + (vt ^ (i << 3))] = (u16)vr[0][i];
#pragma unroll
    for (int i = 0; i < 8; ++i) vT_sm[buf][(vd0 + 8 + i) * 64 + (vt ^ (i << 3))] = (u16)vr[1][i];
  };

  const int nkt = j + 1;
  short8 vr[2], vrn[2];
  stageK(0, 0);
  loadV(0, vr);
  writeV(0, vr);
  int cur = 0;
  for (int kt = 0; kt < nkt; ++kt) {
    __syncthreads();
    if (kt + 1 < nkt) { stageK(kt + 1, cur ^ 1); loadV(kt + 1, vrn); }

    f32x4 s[4] = {};
#pragma unroll
    for (int nt = 0; nt < 4; ++nt)
#pragma unroll
      for (int half = 0; half < 2; ++half) {
        short8 bk = *(const short8*)&k_sm[cur][(nt * 16 + l16) * 64 +
                                              (((half * 4 + quad) ^ (l16 & 7)) << 3)];
        s[nt] = __builtin_amdgcn_mfma_f32_16x16x32_bf16(aq[half], bk, s[nt], 0, 0, 0);
      }
#pragma unroll
    for (int nt = 0; nt < 4; ++nt)
#pragma unroll
      for (int i = 0; i < 4; ++i) {
        const int col = kt * 64 + nt * 16 + l16;
        const int row = j * 64 + wave * 16 + quad * 4 + i;
        float sv = s[nt][i] * 0.125f;
        s[nt][i] = (col <= row) ? sv : -INFINITY;
      }
    float rm[4], mn[4], alpha[4], rs[4], p[4][4];
#pragma unroll
    for (int i = 0; i < 4; ++i)
      rm[i] = fmaxf(fmaxf(s[0][i], s[1][i]), fmaxf(s[2][i], s[3][i]));
#pragma unroll
    for (int off = 1; off < 16; off <<= 1)
#pragma unroll
      for (int i = 0; i < 4; ++i) rm[i] = fmaxf(rm[i], __shfl_xor(rm[i], off));
#pragma unroll
    for (int i = 0; i < 4; ++i) {
      mn[i] = fmaxf(m_i[i], rm[i]);
      alpha[i] = __expf(m_i[i] - mn[i]);
      m_i[i] = mn[i];
#pragma unroll
      for (int nt = 0; nt < 4; ++nt) p[nt][i] = __expf(s[nt][i] - mn[i]);
      rs[i] = (p[0][i] + p[1][i]) + (p[2][i] + p[3][i]);
    }
#pragma unroll
    for (int off = 1; off < 16; off <<= 1)
#pragma unroll
      for (int i = 0; i < 4; ++i) rs[i] += __shfl_xor(rs[i], off);
#pragma unroll
    for (int i = 0; i < 4; ++i) l_i[i] = l_i[i] * alpha[i] + rs[i];
#pragma unroll
    for (int nt = 0; nt < 4; ++nt)
#pragma unroll
      for (int i = 0; i < 4; ++i) oacc[nt][i] *= alpha[i];
    u16* pw = p_sm + wave * 1024;
#pragma unroll
    for (int i = 0; i < 4; ++i) {
      const int pr = quad * 4 + i;
#pragma unroll
      for (int nt = 0; nt < 4; ++nt)
        pw[pr * 64 + ((nt * 16 + l16) ^ ((pr & 7) << 3))] = f2b(p[nt][i]);
    }
    asm volatile("s_waitcnt lgkmcnt(0)" ::: "memory");
    short8 pf[2];
#pragma unroll
    for (int kh = 0; kh < 2; ++kh)
      pf[kh] = *(const short8*)&pw[l16 * 64 + (((kh * 4 + quad) ^ (l16 & 7)) << 3)];
#pragma unroll
    for (int nt = 0; nt < 4; ++nt)
#pragma unroll
      for (int kh = 0; kh < 2; ++kh) {
        short8 bv = *(const short8*)&vT_sm[cur][(nt * 16 + l16) * 64 +
                                               (((kh * 4 + quad) ^ (l16 & 7)) << 3)];
        oacc[nt] = __builtin_amdgcn_mfma_f32_16x16x32_bf16(pf[kh], bv, oacc[nt], 0, 0, 0);
      }

    if (kt + 1 < nkt) writeV(cur ^ 1, vrn);
    cur ^= 1;
  }
#pragma unroll
  for (int nt = 0; nt < 4; ++nt)
#pragma unroll
    for (int i = 0; i < 4; ++i) {
      const int row = j * 64 + wave * 16 + quad * 4 + i;
      const float ov = oacc[nt][i] / l_i[i];
      o[(size_t)(b * T_ + row) * 512 + h * 64 + nt * 16 + l16] = f2b(ov);
    }
}

// ---------------------------------------------------------------------------
// Row LN helper: hv = this thread's 2 elems of a 512-row; writes bf16x2.
// ---------------------------------------------------------------------------
__device__ __forceinline__ void ln_emit(float2 hv, const float* __restrict__ sc,
                                        const float* __restrict__ bi, int tid,
                                        unsigned* __restrict__ yrow)
{
  float s = hv.x + hv.y;
  float q = hv.x * hv.x + hv.y * hv.y;
  for (int off = 32; off; off >>= 1) { s += __shfl_down(s, off); q += __shfl_down(q, off); }
  __shared__ float red[8];
  const int wave = tid >> 6, lane = tid & 63;
  if (!lane) { red[wave] = s; red[4 + wave] = q; }
  __syncthreads();
  if (tid == 0) {
    float ts = 0, tq = 0;
    for (int w = 0; w < 4; ++w) { ts += red[w]; tq += red[4 + w]; }
    red[0] = ts; red[4] = tq;
  }
  __syncthreads();
  const float mu = red[0] * (1.f / 512.f);
  const float var = red[4] * (1.f / 512.f) - mu * mu;
  const float rstd = rsqrtf(var + 1e-5f);
  const float y0 = (hv.x - mu) * rstd * sc[tid * 2]     + bi[tid * 2];
  const float y1 = (hv.y - mu) * rstd * sc[tid * 2 + 1] + bi[tid * 2 + 1];
  yrow[tid] = ((unsigned)f2b(y1) << 16) | (unsigned)f2b(y0);
}

// ---------------------------------------------------------------------------
// Split-K reduce + residual + bias into h, fused with the NEXT op's LN (or a
// plain bf16 copy when DOLN=0). Row per block, 256 threads, float2/thread.
// ---------------------------------------------------------------------------
template<int NS, int DOLN>
__global__ __launch_bounds__(256) void resid_ln_kernel(
    const float* __restrict__ part, const float* __restrict__ bias,
    float* __restrict__ h, const float* __restrict__ sc,
    const float* __restrict__ bi, u16* __restrict__ y)
{
  const int row = blockIdx.x, tid = threadIdx.x;
  float2 hv = ((const float2*)(h + (size_t)row * 512))[tid];
  const float2 bv = ((const float2*)bias)[tid];
#pragma unroll
  for (int s = 0; s < NS; ++s) {
    const float2 pv = ((const float2*)(part + ((size_t)s * TOKENS + row) * 512))[tid];
    hv.x += pv.x; hv.y += pv.y;
  }
  hv.x += bv.x; hv.y += bv.y;
  ((float2*)(h + (size_t)row * 512))[tid] = hv;
  if (DOLN)
    ln_emit(hv, sc, bi, tid, (unsigned*)(y + (size_t)row * 512));
  else
    ((unsigned*)y)[(size_t)row * 256 + tid] = ((unsigned)f2b(hv.y) << 16) | (unsigned)f2b(hv.x);
}

// ---------------------------------------------------------------------------
// Embedding + ln1(layer 0), with the QKV bias_cat folded in (blocks 0..35).
// ---------------------------------------------------------------------------
__global__ __launch_bounds__(256) void embed_ln_kernel(const int* __restrict__ x,
                                                       const float* __restrict__ tok,
                                                       const float* __restrict__ pos,
                                                       const float* __restrict__ sc,
                                                       const float* __restrict__ bi,
                                                       const float* __restrict__ bq,
                                                       const float* __restrict__ bk,
                                                       const float* __restrict__ bv,
                                                       float* __restrict__ bqkv,
                                                       float* __restrict__ h,
                                                       u16* __restrict__ y)
{
  const int row = blockIdx.x, tid = threadIdx.x;
  if (row < 36) {
    const int i = row * 256 + tid;
    if (i < L_ * 1536) {
      const int l = i / 1536, c = i % 1536;
      bqkv[i] = (c < 512) ? bq[l * 512 + c]
              : (c < 1024) ? bk[l * 512 + c - 512] : bv[l * 512 + c - 1024];
    }
  }
  const int t = row & (T_ - 1);
  const int tk = x[row];
  const float2 a = ((const float2*)tok)[(size_t)tk * 256 + tid];
  const float2 p = ((const float2*)pos)[(size_t)t * 256 + tid];
  float2 hv = make_float2(a.x + p.x, a.y + p.y);
  ((float2*)(h + (size_t)row * 512))[tid] = hv;
  ln_emit(hv, sc, bi, tid, (unsigned*)(y + (size_t)row * 512));
}

// ---------------------------------------------------------------------------
// ALL weight transposes (fp32 -> bf16, [K][N] -> [N][K]) in ONE launch.
// Flat block id decodes which weight/tile. 34432 blocks of (32,8).
// ---------------------------------------------------------------------------
__global__ void transW_all(const float* __restrict__ Wq, const float* __restrict__ Wk,
                           const float* __restrict__ Wv, const float* __restrict__ Wo,
                           const float* __restrict__ W1, const float* __restrict__ W2,
                           const float* __restrict__ Wout,
                           u16* __restrict__ qkvT, u16* __restrict__ WoT,
                           u16* __restrict__ W1T, u16* __restrict__ W2T,
                           u16* __restrict__ WoutT)
{
  __shared__ float tile[32][33];
  int f = blockIdx.x;
  const float* S; u16* D; int N, Kd, n0, k0;
  if (f < 16000) {                       // Wout [512][32000] -> WoutT [32000][512]
    S = Wout; D = WoutT; N = 32000; Kd = 512;
    n0 = (f % 1000) * 32; k0 = (f / 1000) * 32;
  } else {
    f -= 16000;
    const int l = f / 3072, r = f % 3072;
    if (r < 1024) {                      // Wq/Wk/Wv/Wo [512][512]
      const int w = r >> 8, rr = r & 255;
      S = (w == 0 ? Wq : w == 1 ? Wk : w == 2 ? Wv : Wo) + (size_t)l * 512 * 512;
      D = (w < 3) ? qkvT + (size_t)l * 1536 * 512 + (size_t)w * 512 * 512
                  : WoT + (size_t)l * 512 * 512;
      N = 512; Kd = 512;
      n0 = (rr & 15) * 32; k0 = (rr >> 4) * 32;
    } else if (r < 2048) {               // W1 [512][2048] -> W1T [2048][512]
      const int rr = r - 1024;
      S = W1 + (size_t)l * 512 * 2048; D = W1T + (size_t)l * 2048 * 512;
      N = 2048; Kd = 512;
      n0 = (rr & 63) * 32; k0 = (rr >> 6) * 32;
    } else {                             // W2 [2048][512] -> W2T [512][2048]
      const int rr = r - 2048;
      S = W2 + (size_t)l * 2048 * 512; D = W2T + (size_t)l * 512 * 2048;
      N = 512; Kd = 2048;
      n0 = (rr & 15) * 32; k0 = (rr >> 4) * 32;
    }
  }
  const int tx = threadIdx.x, ty = threadIdx.y;
#pragma unroll
  for (int i = 0; i < 4; ++i)
    tile[ty + 8 * i][tx] = S[(size_t)(k0 + ty + 8 * i) * N + n0 + tx];
  __syncthreads();
#pragma unroll
  for (int i = 0; i < 4; ++i)
    D[(size_t)(n0 + ty + 8 * i) * Kd + k0 + tx] = f2b(tile[tx][ty + 8 * i]);
}

// ---------------------------------------------------------------------------
extern "C" void kernel_launch(void* const* d_in, const int* in_sizes, int n_in,
                              void* d_out, int out_size, void* d_ws, size_t ws_size,
                              hipStream_t stream) {
  const int*   x     = (const int*)d_in[0];
  const float* tok   = (const float*)d_in[1];
  const float* pos   = (const float*)d_in[2];
  const float* Wq    = (const float*)d_in[3];
  const float* bq    = (const float*)d_in[4];
  const float* Wk    = (const float*)d_in[5];
  const float* bk    = (const float*)d_in[6];
  const float* Wv    = (const float*)d_in[7];
  const float* bv    = (const float*)d_in[8];
  const float* Wo    = (const float*)d_in[9];
  const float* bo    = (const float*)d_in[10];
  const float* ln1s  = (const float*)d_in[11];
  const float* ln1b  = (const float*)d_in[12];
  const float* ln2s  = (const float*)d_in[13];
  const float* ln2b  = (const float*)d_in[14];
  const float* W1    = (const float*)d_in[15];
  const float* b1    = (const float*)d_in[16];
  const float* W2    = (const float*)d_in[17];
  const float* b2    = (const float*)d_in[18];
  const float* Wout  = (const float*)d_in[19];
  const float* bout  = (const float*)d_in[20];

  char* ws = (char*)d_ws;
  size_t off = 0;
  auto alloc = [&](size_t bytes) { char* p = ws + off; off += (bytes + 255) & ~(size_t)255; return p; };
  u16*   qkvT  = (u16*)alloc((size_t)L_ * 1536 * 512 * 2);
  u16*   WoT   = (u16*)alloc((size_t)L_ * 512 * 512 * 2);
  u16*   W1T   = (u16*)alloc((size_t)L_ * 2048 * 512 * 2);
  u16*   W2T   = (u16*)alloc((size_t)L_ * 512 * 2048 * 2);
  u16*   WoutT = (u16*)alloc((size_t)V_ * 512 * 2);
  float* bqkv  = (float*)alloc((size_t)L_ * 1536 * 4);
  float* h     = (float*)alloc((size_t)TOKENS * 512 * 4);
  u16*   y     = (u16*)alloc((size_t)TOKENS * 512 * 2);
  u16*   qkv   = (u16*)alloc((size_t)TOKENS * 1536 * 2);
  u16*   obuf  = (u16*)alloc((size_t)TOKENS * 512 * 2);
  u16*   ff    = (u16*)alloc((size_t)TOKENS * 2048 * 2);
  u16*   hb    = (u16*)alloc((size_t)TOKENS * 512 * 2);
  float* part  = (float*)alloc((size_t)2 * TOKENS * 512 * 4);  // split-K partials
  (void)ws_size; (void)in_sizes; (void)n_in; (void)out_size;

  // ALL weight prep in one launch
  transW_all<<<34432, dim3(32, 8), 0, stream>>>(Wq, Wk, Wv, Wo, W1, W2, Wout,
                                                qkvT, WoT, W1T, W2T, WoutT);

  // embed + ln1(layer 0) + bias_cat
  embed_ln_kernel<<<TOKENS, 256, 0, stream>>>(x, tok, pos, ln1s, ln1b,
                                              bq, bk, bv, bqkv, h, y);

  for (int l = 0; l < L_; ++l) {
    // QKV: 768 blocks (3/CU)
    gemm_bt64<1, 0><<<dim3(12, 64), 256, 0, stream>>>(
        y, qkvT + (size_t)l * 1536 * 512, bqkv + l * 1536, qkv, TOKENS, 1536, 512, 1536);
    attn_kernel<<<dim3(32, 16), 256, 0, stream>>>(qkv, obuf);
    // Wo projection: 64-tile + split-K=2 -> 512 blocks, kLen=256
    gemm_sk64<<<dim3(4, 64, 2), 256, 0, stream>>>(
        obuf, WoT + (size_t)l * 512 * 512, part, TOKENS, 512, 512, 256);
    resid_ln_kernel<2, 1><<<TOKENS, 256, 0, stream>>>(
        part, bo + l * 512, h, ln2s + l * 512, ln2b + l * 512, y);
    // FF1: 1024 blocks (4/CU)
    gemm_bt64<1, 1><<<dim3(16, 64), 256, 0, stream>>>(
        y, W1T + (size_t)l * 2048 * 512, b1 + l * 2048, ff, TOKENS, 2048, 512, 2048);
    // FF2: 64-tile + split-K=2 -> 512 blocks, kLen=1024
    gemm_sk64<<<dim3(4, 64, 2), 256, 0, stream>>>(
        ff, W2T + (size_t)l * 512 * 2048, part, TOKENS, 512, 2048, 1024);
    if (l < L_ - 1)
      resid_ln_kernel<2, 1><<<TOKENS, 256, 0, stream>>>(
          part, b2 + l * 512, h, ln1s + (l + 1) * 512, ln1b + (l + 1) * 512, y);
    else
      resid_ln_kernel<2, 0><<<TOKENS, 256, 0, stream>>>(
          part, b2 + l * 512, h, nullptr, nullptr, hb);
  }

  gemm_bt<0, 0><<<dim3(250, 32), 256, 0, stream>>>(
      hb, WoutT, bout, (float*)d_out, TOKENS, V_, 512, V_);
}